// Round 2
// baseline (359.112 us; speedup 1.0000x reference)
//
#include <hip/hip_runtime.h>
#include <hip/hip_bf16.h>

#define BATCH 16
#define SEQ   2048
#define DK    128

typedef __attribute__((ext_vector_type(8))) short short8v;   // 8 bf16 = 4 VGPR
typedef __attribute__((ext_vector_type(4))) short short4v;   // 4 bf16 = 2 VGPR
typedef __attribute__((ext_vector_type(4))) float float4v;   // MFMA 16x16 C/D

__device__ inline short f2bf(float f) {
    __hip_bfloat16 h = __float2bfloat16(f);
    unsigned short u;
    __builtin_memcpy(&u, &h, sizeof(u));
    return (short)u;
}

// ---------------- prepass: K fp32 -> bf16 (row-major) ----------------
__global__ __launch_bounds__(256)
void conv_k_kernel(const float* __restrict__ k, short* __restrict__ kb)
{
    size_t i = ((size_t)blockIdx.x * 256 + threadIdx.x) * 8;
    float4 a = *reinterpret_cast<const float4*>(k + i);
    float4 b = *reinterpret_cast<const float4*>(k + i + 4);
    short8v t;
    t[0] = f2bf(a.x); t[1] = f2bf(a.y); t[2] = f2bf(a.z); t[3] = f2bf(a.w);
    t[4] = f2bf(b.x); t[5] = f2bf(b.y); t[6] = f2bf(b.z); t[7] = f2bf(b.w);
    *reinterpret_cast<short8v*>(kb + i) = t;
}

// ---------------- prepass: V fp32 [b][s][d] -> bf16 Vt [b][d][s] ------
__global__ __launch_bounds__(256)
void transpose_v_kernel(const float* __restrict__ v, short* __restrict__ vt)
{
    __shared__ float tile[32][33];
    const int tx = threadIdx.x & 31;
    const int ty = threadIdx.x >> 5;              // 0..7
    const int b  = blockIdx.z;
    const int s0 = blockIdx.x * 32;
    const int d0 = blockIdx.y * 32;

    const float* vb = v + ((size_t)b * SEQ + s0) * DK + d0;
#pragma unroll
    for (int i = 0; i < 4; ++i) {
        int r = ty + 8 * i;                       // kv row within tile
        tile[r][tx] = vb[(size_t)r * DK + tx];
    }
    __syncthreads();
    short* vtb = vt + ((size_t)b * DK + d0) * SEQ + s0;
#pragma unroll
    for (int i = 0; i < 4; ++i) {
        int r = ty + 8 * i;                       // d row within tile
        vtb[(size_t)r * SEQ + tx] = f2bf(tile[tx][r]);
    }
}

// ---------------- main: flash attention, bf16 MFMA --------------------
// Block = 512 threads = 8 waves: wave = qt (0..3) + 4*half (0..1).
// Each wave: 16 q rows, kv range of 1024, kv tiles of 32 (2 x 16 subtiles).
// S^T via mfma(K, Q): lane holds S^T[kv=4*grp+r][q=lane&15] (verified r1).
// PV zero-padded 16x16x32: A = {p0..p3,0,0,0,0}, B = V rows via Vt (dup).
// KV-split halves merged once via LDS at the end.
__global__ __launch_bounds__(512, 4)
void attn_fwd_fast(const float* __restrict__ q,
                   const short* __restrict__ kb,
                   const short* __restrict__ vt,
                   float* __restrict__ out)
{
    __shared__ float smO[4][16][132];
    __shared__ float smM[4][16];
    __shared__ float smL[4][16];

    const int lane = threadIdx.x & 63;
    const int wave = threadIdx.x >> 6;            // 0..7
    const int qt   = wave & 3;
    const int half = wave >> 2;
    const int b    = blockIdx.y;
    const int q0   = blockIdx.x * 64 + qt * 16;

    const int row = lane & 15;
    const int grp = lane >> 4;

    const float scale = 0.08838834764831845f;     // 1/sqrt(128)

    // Q fragments (fp32 -> bf16 inline; read once per wave)
    const float* qb = q + ((size_t)b * SEQ + q0) * DK;
    short8v qf[4];
#pragma unroll
    for (int c = 0; c < 4; ++c) {
        const float* p = qb + row * DK + c * 32 + grp * 8;
        float4 x = *reinterpret_cast<const float4*>(p);
        float4 y = *reinterpret_cast<const float4*>(p + 4);
        short8v t;
        t[0] = f2bf(x.x); t[1] = f2bf(x.y); t[2] = f2bf(x.z); t[3] = f2bf(x.w);
        t[4] = f2bf(y.x); t[5] = f2bf(y.y); t[6] = f2bf(y.z); t[7] = f2bf(y.w);
        qf[c] = t;
    }

    const short* kbb = kb + (size_t)b * SEQ * DK;
    const short* vtb = vt + (size_t)b * DK * SEQ;

    float m_run = -1e30f;
    float l_run = 0.0f;
    float4v o[8];
#pragma unroll
    for (int i = 0; i < 8; ++i) { o[i][0] = 0.f; o[i][1] = 0.f; o[i][2] = 0.f; o[i][3] = 0.f; }

    const int kv_lo = half * (SEQ / 2);
    for (int kv0 = kv_lo; kv0 < kv_lo + SEQ / 2; kv0 += 32) {
        // K fragments for the two 16-kv subtiles (direct bf16 16B loads)
        short8v kf0[4], kf1[4];
        {
            const short* p0 = kbb + (size_t)(kv0 + row) * DK + grp * 8;
            const short* p1 = p0 + 16 * DK;
#pragma unroll
            for (int c = 0; c < 4; ++c) {
                kf0[c] = *reinterpret_cast<const short8v*>(p0 + c * 32);
                kf1[c] = *reinterpret_cast<const short8v*>(p1 + c * 32);
            }
        }

        float4v s0; s0[0] = 0.f; s0[1] = 0.f; s0[2] = 0.f; s0[3] = 0.f;
        float4v s1; s1[0] = 0.f; s1[1] = 0.f; s1[2] = 0.f; s1[3] = 0.f;
#pragma unroll
        for (int c = 0; c < 4; ++c) {
            s0 = __builtin_amdgcn_mfma_f32_16x16x32_bf16(kf0[c], qf[c], s0, 0, 0, 0);
            s1 = __builtin_amdgcn_mfma_f32_16x16x32_bf16(kf1[c], qf[c], s1, 0, 0, 0);
        }

        // joint online softmax over 32 kv (raw-score domain, scale in exp)
        float tmax = fmaxf(fmaxf(fmaxf(s0[0], s0[1]), fmaxf(s0[2], s0[3])),
                           fmaxf(fmaxf(s1[0], s1[1]), fmaxf(s1[2], s1[3])));
        tmax = fmaxf(tmax, __shfl_xor(tmax, 16));
        tmax = fmaxf(tmax, __shfl_xor(tmax, 32));
        const float mnew = fmaxf(m_run, tmax);

        float pr0[4], pr1[4];
        float tsum = 0.f;
#pragma unroll
        for (int r = 0; r < 4; ++r) {
            pr0[r] = __expf((s0[r] - mnew) * scale);
            pr1[r] = __expf((s1[r] - mnew) * scale);
            tsum += pr0[r] + pr1[r];
        }
        tsum += __shfl_xor(tsum, 16);
        tsum += __shfl_xor(tsum, 32);

        const float alpha = __expf((m_run - mnew) * scale);
        l_run = l_run * alpha + tsum;
        m_run = mnew;

        float aq[4];
#pragma unroll
        for (int r = 0; r < 4; ++r) aq[r] = __shfl(alpha, grp * 4 + r);
#pragma unroll
        for (int dblk = 0; dblk < 8; ++dblk)
#pragma unroll
            for (int r = 0; r < 4; ++r) o[dblk][r] *= aq[r];

        short8v pf0, pf1;
        pf0[0] = f2bf(pr0[0]); pf0[1] = f2bf(pr0[1]); pf0[2] = f2bf(pr0[2]); pf0[3] = f2bf(pr0[3]);
        pf0[4] = 0; pf0[5] = 0; pf0[6] = 0; pf0[7] = 0;
        pf1[0] = f2bf(pr1[0]); pf1[1] = f2bf(pr1[1]); pf1[2] = f2bf(pr1[2]); pf1[3] = f2bf(pr1[3]);
        pf1[4] = 0; pf1[5] = 0; pf1[6] = 0; pf1[7] = 0;

        // PV: V rows kv = 4*grp + j via Vt (kv-contiguous 8B loads), duplicated
#pragma unroll
        for (int dblk = 0; dblk < 8; ++dblk) {
            const short* vp = vtb + (size_t)(dblk * 16 + row) * SEQ + kv0 + 4 * grp;
            short4v v0 = *reinterpret_cast<const short4v*>(vp);
            short4v v1 = *reinterpret_cast<const short4v*>(vp + 16);
            short8v vf0, vf1;
            vf0[0] = v0[0]; vf0[1] = v0[1]; vf0[2] = v0[2]; vf0[3] = v0[3];
            vf0[4] = v0[0]; vf0[5] = v0[1]; vf0[6] = v0[2]; vf0[7] = v0[3];
            vf1[0] = v1[0]; vf1[1] = v1[1]; vf1[2] = v1[2]; vf1[3] = v1[3];
            vf1[4] = v1[0]; vf1[5] = v1[1]; vf1[6] = v1[2]; vf1[7] = v1[3];
            o[dblk] = __builtin_amdgcn_mfma_f32_16x16x32_bf16(pf0, vf0, o[dblk], 0, 0, 0);
            o[dblk] = __builtin_amdgcn_mfma_f32_16x16x32_bf16(pf1, vf1, o[dblk], 0, 0, 0);
        }
    }

    // merge the two kv halves via LDS
    if (half == 1) {
        smM[qt][row] = m_run;
        smL[qt][row] = l_run;
#pragma unroll
        for (int dblk = 0; dblk < 8; ++dblk)
#pragma unroll
            for (int r = 0; r < 4; ++r)
                smO[qt][grp * 4 + r][dblk * 16 + row] = o[dblk][r];
    }
    __syncthreads();
    if (half == 0) {
        const float m1 = smM[qt][row];
        const float l1 = smL[qt][row];
        const float mf = fmaxf(m_run, m1);
        const float a0 = __expf((m_run - mf) * scale);
        const float a1 = __expf((m1 - mf) * scale);
        const float lf = l_run * a0 + l1 * a1;
        const float li = 1.0f / lf;

        float a0q[4], a1q[4], liq[4];
#pragma unroll
        for (int r = 0; r < 4; ++r) {
            a0q[r] = __shfl(a0, grp * 4 + r);
            a1q[r] = __shfl(a1, grp * 4 + r);
            liq[r] = __shfl(li, grp * 4 + r);
        }

        float* ob = out + ((size_t)b * SEQ + q0) * DK;
#pragma unroll
        for (int dblk = 0; dblk < 8; ++dblk)
#pragma unroll
            for (int r = 0; r < 4; ++r) {
                float val = (o[dblk][r] * a0q[r]
                             + smO[qt][grp * 4 + r][dblk * 16 + row] * a1q[r]) * liq[r];
                ob[(size_t)(grp * 4 + r) * DK + dblk * 16 + row] = val;
            }
    }
}

// ---------------- fallback (round-1 kernel) if ws too small -----------
__global__ __launch_bounds__(256)
void attn_fwd_slow(const float* __restrict__ q,
                   const float* __restrict__ k,
                   const float* __restrict__ v,
                   float* __restrict__ out)
{
    const int lane = threadIdx.x & 63;
    const int wave = threadIdx.x >> 6;
    const int b    = blockIdx.y;
    const int q0   = blockIdx.x * 64 + wave * 16;
    const int row = lane & 15;
    const int grp = lane >> 4;

    const float* qb = q + ((size_t)b * SEQ + q0) * DK;
    const float* kbp = k + (size_t)b * SEQ * DK;
    const float* vbp = v + (size_t)b * SEQ * DK;

    short8v qf[4];
#pragma unroll
    for (int c = 0; c < 4; ++c) {
        const float* p = qb + row * DK + c * 32 + grp * 8;
        float4 x = *reinterpret_cast<const float4*>(p);
        float4 y = *reinterpret_cast<const float4*>(p + 4);
        short8v t;
        t[0] = f2bf(x.x); t[1] = f2bf(x.y); t[2] = f2bf(x.z); t[3] = f2bf(x.w);
        t[4] = f2bf(y.x); t[5] = f2bf(y.y); t[6] = f2bf(y.z); t[7] = f2bf(y.w);
        qf[c] = t;
    }

    float m_run = -1e30f, l_run = 0.0f;
    float4v o[8];
#pragma unroll
    for (int i = 0; i < 8; ++i) { o[i][0]=0.f; o[i][1]=0.f; o[i][2]=0.f; o[i][3]=0.f; }
    const float scale = 0.08838834764831845f;

    for (int kv0 = 0; kv0 < SEQ; kv0 += 16) {
        short8v kf[4];
        const float* kp0 = kbp + (size_t)(kv0 + row) * DK + grp * 8;
#pragma unroll
        for (int c = 0; c < 4; ++c) {
            const float* p = kp0 + c * 32;
            float4 x = *reinterpret_cast<const float4*>(p);
            float4 y = *reinterpret_cast<const float4*>(p + 4);
            short8v t;
            t[0] = f2bf(x.x); t[1] = f2bf(x.y); t[2] = f2bf(x.z); t[3] = f2bf(x.w);
            t[4] = f2bf(y.x); t[5] = f2bf(y.y); t[6] = f2bf(y.z); t[7] = f2bf(y.w);
            kf[c] = t;
        }
        short8v vf[8];
#pragma unroll
        for (int dblk = 0; dblk < 8; ++dblk) {
            const float* p = vbp + (size_t)(kv0 + 4 * grp) * DK + dblk * 16 + row;
            short b0 = f2bf(p[0]);
            short b1 = f2bf(p[DK]);
            short b2 = f2bf(p[2 * DK]);
            short b3 = f2bf(p[3 * DK]);
            short8v t;
            t[0]=b0; t[1]=b1; t[2]=b2; t[3]=b3; t[4]=b0; t[5]=b1; t[6]=b2; t[7]=b3;
            vf[dblk] = t;
        }
        float4v s; s[0]=0.f; s[1]=0.f; s[2]=0.f; s[3]=0.f;
#pragma unroll
        for (int c = 0; c < 4; ++c)
            s = __builtin_amdgcn_mfma_f32_16x16x32_bf16(kf[c], qf[c], s, 0, 0, 0);

        float sv[4]; float tmax = -1e30f;
#pragma unroll
        for (int r = 0; r < 4; ++r) { sv[r] = s[r] * scale; tmax = fmaxf(tmax, sv[r]); }
        tmax = fmaxf(tmax, __shfl_xor(tmax, 16));
        tmax = fmaxf(tmax, __shfl_xor(tmax, 32));
        const float mnew = fmaxf(m_run, tmax);
        float pr[4]; float tsum = 0.f;
#pragma unroll
        for (int r = 0; r < 4; ++r) { pr[r] = __expf(sv[r] - mnew); tsum += pr[r]; }
        tsum += __shfl_xor(tsum, 16);
        tsum += __shfl_xor(tsum, 32);
        const float alpha = __expf(m_run - mnew);
        l_run = l_run * alpha + tsum;
        m_run = mnew;
        float aq[4];
#pragma unroll
        for (int r = 0; r < 4; ++r) aq[r] = __shfl(alpha, grp * 4 + r);
#pragma unroll
        for (int dblk = 0; dblk < 8; ++dblk)
#pragma unroll
            for (int r = 0; r < 4; ++r) o[dblk][r] *= aq[r];

        short8v pf;
        pf[0]=f2bf(pr[0]); pf[1]=f2bf(pr[1]); pf[2]=f2bf(pr[2]); pf[3]=f2bf(pr[3]);
        pf[4]=0; pf[5]=0; pf[6]=0; pf[7]=0;
#pragma unroll
        for (int dblk = 0; dblk < 8; ++dblk)
            o[dblk] = __builtin_amdgcn_mfma_f32_16x16x32_bf16(pf, vf[dblk], o[dblk], 0, 0, 0);
    }

    const float linv = 1.0f / l_run;
    float li[4];
#pragma unroll
    for (int r = 0; r < 4; ++r) li[r] = __shfl(linv, grp * 4 + r);
    float* ob = out + ((size_t)b * SEQ + q0) * DK;
#pragma unroll
    for (int dblk = 0; dblk < 8; ++dblk)
#pragma unroll
        for (int r = 0; r < 4; ++r)
            ob[(size_t)(grp * 4 + r) * DK + dblk * 16 + row] = o[dblk][r] * li[r];
}

extern "C" void kernel_launch(void* const* d_in, const int* in_sizes, int n_in,
                              void* d_out, int out_size, void* d_ws, size_t ws_size,
                              hipStream_t stream) {
    const float* q = (const float*)d_in[0];
    const float* k = (const float*)d_in[1];
    const float* v = (const float*)d_in[2];
    float* out = (float*)d_out;

    const size_t kb_bytes = (size_t)BATCH * SEQ * DK * sizeof(short);
    const size_t need = 2 * kb_bytes;

    if (ws_size >= need) {
        short* kb = (short*)d_ws;
        short* vt = (short*)((char*)d_ws + kb_bytes);
        hipLaunchKernelGGL(conv_k_kernel, dim3(2048), dim3(256), 0, stream, k, kb);
        hipLaunchKernelGGL(transpose_v_kernel, dim3(SEQ / 32, DK / 32, BATCH), dim3(256), 0, stream, v, vt);
        hipLaunchKernelGGL(attn_fwd_fast, dim3(SEQ / 64, BATCH), dim3(512), 0, stream, q, kb, vt, out);
    } else {
        hipLaunchKernelGGL(attn_fwd_slow, dim3(SEQ / 64, BATCH), dim3(256), 0, stream, q, k, v, out);
    }
}

// Round 3
// 89.252 us; speedup vs baseline: 4.0236x; 4.0236x over previous
//
#include <hip/hip_runtime.h>
#include <hip/hip_bf16.h>

#define BATCH 16
#define SEQ   2048
#define DK    128
#define SC2   0.12751744f   // (1/sqrt(128)) * log2(e)

typedef __attribute__((ext_vector_type(8))) short short8v;
typedef __attribute__((ext_vector_type(4))) short short4v;
typedef __attribute__((ext_vector_type(4))) float float4v;

typedef const __attribute__((address_space(1))) unsigned int* gas_t;
typedef __attribute__((address_space(3))) unsigned int* las_t;

__device__ inline void gl_lds16(const void* g, void* l) {
    // width-16 global->LDS DMA; LDS dest = wave-uniform base + lane*16
    __builtin_amdgcn_global_load_lds((gas_t)g, (las_t)l, 16, 0, 0);
}

__device__ inline short f2bf(float f) {
    __hip_bfloat16 h = __float2bfloat16(f);
    unsigned short u;
    __builtin_memcpy(&u, &h, sizeof(u));
    return (short)u;
}

// ---------------- prepass: K fp32 -> bf16 (row-major) ----------------
__global__ __launch_bounds__(256)
void conv_k_kernel(const float* __restrict__ k, short* __restrict__ kb)
{
    size_t i = ((size_t)blockIdx.x * 256 + threadIdx.x) * 8;
    float4 a = *reinterpret_cast<const float4*>(k + i);
    float4 b = *reinterpret_cast<const float4*>(k + i + 4);
    short8v t;
    t[0] = f2bf(a.x); t[1] = f2bf(a.y); t[2] = f2bf(a.z); t[3] = f2bf(a.w);
    t[4] = f2bf(b.x); t[5] = f2bf(b.y); t[6] = f2bf(b.z); t[7] = f2bf(b.w);
    *reinterpret_cast<short8v*>(kb + i) = t;
}

// ---------------- prepass: V fp32 [b][s][d] -> bf16 Vt [b][d][s] ------
__global__ __launch_bounds__(256)
void transpose_v_kernel(const float* __restrict__ v, short* __restrict__ vt)
{
    __shared__ float tile[32][33];
    const int tx = threadIdx.x & 31;
    const int ty = threadIdx.x >> 5;              // 0..7
    const int b  = blockIdx.z;
    const int s0 = blockIdx.x * 32;
    const int d0 = blockIdx.y * 32;

    const float* vb = v + ((size_t)b * SEQ + s0) * DK + d0;
#pragma unroll
    for (int i = 0; i < 4; ++i) {
        int r = ty + 8 * i;
        tile[r][tx] = vb[(size_t)r * DK + tx];
    }
    __syncthreads();
    short* vtb = vt + ((size_t)b * DK + d0) * SEQ + s0;
#pragma unroll
    for (int i = 0; i < 4; ++i) {
        int r = ty + 8 * i;
        vtb[(size_t)r * SEQ + tx] = f2bf(tile[tx][r]);
    }
}

// ---------------- main: flash attention, LDS-staged -------------------
// Block = 512 thr = 8 waves: qt = wave&3 (16 q rows each), h = wave>>2 (kv half).
// Per KVBLK=64 tile: whole block stages K[64][128]+V[128][64] bf16 for both
// halves via global_load_lds (linear dest, pre-swizzled src, swizzled reads:
// byte ^= (row&7)<<4, 16B granule -- G4 fix for 256B/128B-row conflicts).
// QK^T swapped (mfma(K,Q)): s[sub] lane holds S^T[kv=sub*16+4*grp+r][q=lane&15].
// PV: pair subs (2p,2p+1) -> full 8-slot A in-lane: k=8g+j <-> kv=32p+4g+j (j<4),
// 32p+16+4g+j-4 (j>=4); B from Vt tile as 2x ds_read_b64. No zero-padding.
__global__ __launch_bounds__(512)
void attn_fwd_v3(const float* __restrict__ q,
                 const short* __restrict__ kb,
                 const short* __restrict__ vt,
                 float* __restrict__ out)
{
    __shared__ __align__(16) char lds[65536];   // K: [2][16KB] @0, V: [2][16KB] @32768; merge aliases @0

    const int tid  = threadIdx.x;
    const int lane = tid & 63;
    const int wave = tid >> 6;         // 0..7
    const int qt   = wave & 3;
    const int h    = wave >> 2;        // kv half
    const int b    = blockIdx.y;
    const int q0   = blockIdx.x * 64 + qt * 16;

    const int row = lane & 15;
    const int grp = lane >> 4;
    const int swz = (row & 7) << 4;

    // ---- Q fragments (fp32 -> bf16, once) ----
    const float* qb = q + ((size_t)b * SEQ + q0) * DK;
    short8v qf[4];
#pragma unroll
    for (int c = 0; c < 4; ++c) {
        const float* p = qb + row * DK + c * 32 + grp * 8;
        float4 x = *reinterpret_cast<const float4*>(p);
        float4 y = *reinterpret_cast<const float4*>(p + 4);
        short8v t;
        t[0] = f2bf(x.x); t[1] = f2bf(x.y); t[2] = f2bf(x.z); t[3] = f2bf(x.w);
        t[4] = f2bf(y.x); t[5] = f2bf(y.y); t[6] = f2bf(y.z); t[7] = f2bf(y.w);
        qf[c] = t;
    }

    // ---- staging constants (per thread) ----
    const char* kB = (const char*)(kb + (size_t)b * SEQ * DK);   // 256B rows
    const char* vB = (const char*)(vt + (size_t)b * DK * SEQ);   // 4096B rows
    const int rowK0 = tid >> 4;                                   // 0..31
    const int offK0 = ((tid & 15) << 4) ^ ((rowK0 & 7) << 4);
    const int rowV0 = tid >> 3;                                   // 0..63
    const int offV0 = ((tid & 7) << 4) ^ ((rowV0 & 7) << 4);
    const int wbase = wave << 10;                                 // wave-uniform LDS chunk base

    const char* Kl = lds + h * 16384;
    const char* Vl = lds + 32768 + h * 16384;

    float m_run = -1e30f;
    float l_run = 0.0f;
    float4v o[8];
#pragma unroll
    for (int i = 0; i < 8; ++i) { o[i][0] = 0.f; o[i][1] = 0.f; o[i][2] = 0.f; o[i][3] = 0.f; }

    for (int t = 0; t < 16; ++t) {
        const int kv0 = t * 64;                   // offset within each half
        __syncthreads();                          // prev tile fully consumed
        // ---- stage both halves' K and V tiles ----
#pragma unroll
        for (int hh = 0; hh < 2; ++hh) {
            const char* ks = kB + (size_t)(hh * 1024 + kv0) * 256;
            const char* vs = vB + (size_t)(hh * 1024 + kv0) * 2;
#pragma unroll
            for (int c = 0; c < 2; ++c) {
                gl_lds16(ks + (size_t)(rowK0 + 32 * c) * 256 + offK0,
                         (void*)(lds + hh * 16384 + c * 8192 + wbase));
                gl_lds16(vs + (size_t)(rowV0 + 64 * c) * 4096 + offV0,
                         (void*)(lds + 32768 + hh * 16384 + c * 8192 + wbase));
            }
        }
        __syncthreads();                          // drains vmcnt before barrier

        // ---- QK^T: 4 subtiles of 16 kv ----
        float4v s[4];
#pragma unroll
        for (int sub = 0; sub < 4; ++sub) {
            s[sub][0] = 0.f; s[sub][1] = 0.f; s[sub][2] = 0.f; s[sub][3] = 0.f;
            const char* kr = Kl + (sub * 16 + row) * 256;
#pragma unroll
            for (int c = 0; c < 4; ++c) {
                short8v kf = *reinterpret_cast<const short8v*>(kr + (((c << 6) | (grp << 4)) ^ swz));
                s[sub] = __builtin_amdgcn_mfma_f32_16x16x32_bf16(kf, qf[c], s[sub], 0, 0, 0);
            }
        }

        // ---- online softmax over 64 kv (16 vals/lane, q = lane&15) ----
        float p[16];
#pragma unroll
        for (int sub = 0; sub < 4; ++sub)
#pragma unroll
            for (int r = 0; r < 4; ++r) p[sub * 4 + r] = s[sub][r];

        float mx = p[0];
#pragma unroll
        for (int i = 1; i < 16; ++i) mx = fmaxf(mx, p[i]);
        mx = fmaxf(mx, __shfl_xor(mx, 16));
        mx = fmaxf(mx, __shfl_xor(mx, 32));
        const float mnew = fmaxf(m_run, mx);

        float tsum = 0.f;
#pragma unroll
        for (int i = 0; i < 16; ++i) { p[i] = exp2f((p[i] - mnew) * SC2); tsum += p[i]; }
        tsum += __shfl_xor(tsum, 16);
        tsum += __shfl_xor(tsum, 32);

        const float alpha = exp2f((m_run - mnew) * SC2);
        l_run = l_run * alpha + tsum;
        m_run = mnew;

        float aq[4];
#pragma unroll
        for (int r = 0; r < 4; ++r) aq[r] = __shfl(alpha, grp * 4 + r);
#pragma unroll
        for (int dblk = 0; dblk < 8; ++dblk)
#pragma unroll
            for (int r = 0; r < 4; ++r) o[dblk][r] *= aq[r];

        // ---- P fragments: pair p2 covers kv 32*p2..32*p2+31, all in-lane ----
        short8v pf[2];
#pragma unroll
        for (int p2 = 0; p2 < 2; ++p2)
#pragma unroll
            for (int j = 0; j < 8; ++j) pf[p2][j] = f2bf(p[8 * p2 + j]);

        // ---- PV: B from V_lds[d][kv], kv slices {32p+4g..+3} and {+16} ----
#pragma unroll
        for (int dblk = 0; dblk < 8; ++dblk) {
            const char* vr = Vl + (dblk * 16 + row) * 128;
#pragma unroll
            for (int p2 = 0; p2 < 2; ++p2) {
                short4v va = *reinterpret_cast<const short4v*>(vr + (((p2 << 6) | (grp << 3)) ^ swz));
                short4v vb4 = *reinterpret_cast<const short4v*>(vr + (((p2 << 6) | 32 | (grp << 3)) ^ swz));
                short8v vf;
                vf[0] = va[0]; vf[1] = va[1]; vf[2] = va[2]; vf[3] = va[3];
                vf[4] = vb4[0]; vf[5] = vb4[1]; vf[6] = vb4[2]; vf[7] = vb4[3];
                o[dblk] = __builtin_amdgcn_mfma_f32_16x16x32_bf16(pf[p2], vf, o[dblk], 0, 0, 0);
            }
        }
    }

    // ---- merge halves via LDS (aliases K/V buffers; all compute done) ----
    float* smO = (float*)lds;                 // [4][16][132] = 33792 B
    float* smM = (float*)(lds + 33792);       // [4][16]
    float* smL = (float*)(lds + 34048);       // [4][16]

    __syncthreads();                          // everyone done reading K/V LDS
    if (h == 1) {
        smM[qt * 16 + row] = m_run;
        smL[qt * 16 + row] = l_run;
#pragma unroll
        for (int dblk = 0; dblk < 8; ++dblk)
#pragma unroll
            for (int r = 0; r < 4; ++r)
                smO[(qt * 16 + grp * 4 + r) * 132 + dblk * 16 + row] = o[dblk][r];
    }
    __syncthreads();
    if (h == 0) {
        const float m1 = smM[qt * 16 + row];
        const float l1 = smL[qt * 16 + row];
        const float mf = fmaxf(m_run, m1);
        const float a0 = exp2f((m_run - mf) * SC2);
        const float a1 = exp2f((m1 - mf) * SC2);
        const float lf = l_run * a0 + l1 * a1;
        const float li = 1.0f / lf;

        float a0q[4], a1q[4], liq[4];
#pragma unroll
        for (int r = 0; r < 4; ++r) {
            a0q[r] = __shfl(a0, grp * 4 + r);
            a1q[r] = __shfl(a1, grp * 4 + r);
            liq[r] = __shfl(li, grp * 4 + r);
        }

        float* ob = out + ((size_t)b * SEQ + q0) * DK;
#pragma unroll
        for (int dblk = 0; dblk < 8; ++dblk)
#pragma unroll
            for (int r = 0; r < 4; ++r) {
                float val = (o[dblk][r] * a0q[r]
                             + smO[(qt * 16 + grp * 4 + r) * 132 + dblk * 16 + row] * a1q[r]) * liq[r];
                ob[(size_t)(grp * 4 + r) * DK + dblk * 16 + row] = val;
            }
    }
}

// ---------------- fallback (round-1 kernel) if ws too small -----------
__global__ __launch_bounds__(256)
void attn_fwd_slow(const float* __restrict__ q,
                   const float* __restrict__ k,
                   const float* __restrict__ v,
                   float* __restrict__ out)
{
    const int lane = threadIdx.x & 63;
    const int wave = threadIdx.x >> 6;
    const int b    = blockIdx.y;
    const int q0   = blockIdx.x * 64 + wave * 16;
    const int row = lane & 15;
    const int grp = lane >> 4;

    const float* qb = q + ((size_t)b * SEQ + q0) * DK;
    const float* kbp = k + (size_t)b * SEQ * DK;
    const float* vbp = v + (size_t)b * SEQ * DK;

    short8v qf[4];
#pragma unroll
    for (int c = 0; c < 4; ++c) {
        const float* p = qb + row * DK + c * 32 + grp * 8;
        float4 x = *reinterpret_cast<const float4*>(p);
        float4 y = *reinterpret_cast<const float4*>(p + 4);
        short8v t;
        t[0] = f2bf(x.x); t[1] = f2bf(x.y); t[2] = f2bf(x.z); t[3] = f2bf(x.w);
        t[4] = f2bf(y.x); t[5] = f2bf(y.y); t[6] = f2bf(y.z); t[7] = f2bf(y.w);
        qf[c] = t;
    }

    float m_run = -1e30f, l_run = 0.0f;
    float4v o[8];
#pragma unroll
    for (int i = 0; i < 8; ++i) { o[i][0]=0.f; o[i][1]=0.f; o[i][2]=0.f; o[i][3]=0.f; }
    const float scale = 0.08838834764831845f;

    for (int kv0 = 0; kv0 < SEQ; kv0 += 16) {
        short8v kf[4];
        const float* kp0 = kbp + (size_t)(kv0 + row) * DK + grp * 8;
#pragma unroll
        for (int c = 0; c < 4; ++c) {
            const float* p = kp0 + c * 32;
            float4 x = *reinterpret_cast<const float4*>(p);
            float4 y = *reinterpret_cast<const float4*>(p + 4);
            short8v t;
            t[0] = f2bf(x.x); t[1] = f2bf(x.y); t[2] = f2bf(x.z); t[3] = f2bf(x.w);
            t[4] = f2bf(y.x); t[5] = f2bf(y.y); t[6] = f2bf(y.z); t[7] = f2bf(y.w);
            kf[c] = t;
        }
        short8v vf[8];
#pragma unroll
        for (int dblk = 0; dblk < 8; ++dblk) {
            const float* p = vbp + (size_t)(kv0 + 4 * grp) * DK + dblk * 16 + row;
            short b0 = f2bf(p[0]);
            short b1 = f2bf(p[DK]);
            short b2 = f2bf(p[2 * DK]);
            short b3 = f2bf(p[3 * DK]);
            short8v t;
            t[0]=b0; t[1]=b1; t[2]=b2; t[3]=b3; t[4]=b0; t[5]=b1; t[6]=b2; t[7]=b3;
            vf[dblk] = t;
        }
        float4v s; s[0]=0.f; s[1]=0.f; s[2]=0.f; s[3]=0.f;
#pragma unroll
        for (int c = 0; c < 4; ++c)
            s = __builtin_amdgcn_mfma_f32_16x16x32_bf16(kf[c], qf[c], s, 0, 0, 0);

        float sv[4]; float tmax = -1e30f;
#pragma unroll
        for (int r = 0; r < 4; ++r) { sv[r] = s[r] * scale; tmax = fmaxf(tmax, sv[r]); }
        tmax = fmaxf(tmax, __shfl_xor(tmax, 16));
        tmax = fmaxf(tmax, __shfl_xor(tmax, 32));
        const float mnew = fmaxf(m_run, tmax);
        float pr[4]; float tsum = 0.f;
#pragma unroll
        for (int r = 0; r < 4; ++r) { pr[r] = __expf(sv[r] - mnew); tsum += pr[r]; }
        tsum += __shfl_xor(tsum, 16);
        tsum += __shfl_xor(tsum, 32);
        const float alpha = __expf(m_run - mnew);
        l_run = l_run * alpha + tsum;
        m_run = mnew;
        float aq[4];
#pragma unroll
        for (int r = 0; r < 4; ++r) aq[r] = __shfl(alpha, grp * 4 + r);
#pragma unroll
        for (int dblk = 0; dblk < 8; ++dblk)
#pragma unroll
            for (int r = 0; r < 4; ++r) o[dblk][r] *= aq[r];

        short8v pf;
        pf[0]=f2bf(pr[0]); pf[1]=f2bf(pr[1]); pf[2]=f2bf(pr[2]); pf[3]=f2bf(pr[3]);
        pf[4]=0; pf[5]=0; pf[6]=0; pf[7]=0;
#pragma unroll
        for (int dblk = 0; dblk < 8; ++dblk)
            o[dblk] = __builtin_amdgcn_mfma_f32_16x16x32_bf16(pf, vf[dblk], o[dblk], 0, 0, 0);
    }

    const float linv = 1.0f / l_run;
    float li[4];
#pragma unroll
    for (int r = 0; r < 4; ++r) li[r] = __shfl(linv, grp * 4 + r);
    float* ob = out + ((size_t)b * SEQ + q0) * DK;
#pragma unroll
    for (int dblk = 0; dblk < 8; ++dblk)
#pragma unroll
        for (int r = 0; r < 4; ++r)
            ob[(size_t)(grp * 4 + r) * DK + dblk * 16 + row] = o[dblk][r] * li[r];
}

extern "C" void kernel_launch(void* const* d_in, const int* in_sizes, int n_in,
                              void* d_out, int out_size, void* d_ws, size_t ws_size,
                              hipStream_t stream) {
    const float* q = (const float*)d_in[0];
    const float* k = (const float*)d_in[1];
    const float* v = (const float*)d_in[2];
    float* out = (float*)d_out;

    const size_t kb_bytes = (size_t)BATCH * SEQ * DK * sizeof(short);
    const size_t need = 2 * kb_bytes;

    if (ws_size >= need) {
        short* kb = (short*)d_ws;
        short* vt = (short*)((char*)d_ws + kb_bytes);
        hipLaunchKernelGGL(conv_k_kernel, dim3(2048), dim3(256), 0, stream, k, kb);
        hipLaunchKernelGGL(transpose_v_kernel, dim3(SEQ / 32, DK / 32, BATCH), dim3(256), 0, stream, v, vt);
        hipLaunchKernelGGL(attn_fwd_v3, dim3(SEQ / 64, BATCH), dim3(512), 0, stream, q, kb, vt, out);
    } else {
        hipLaunchKernelGGL(attn_fwd_slow, dim3(SEQ / 64, BATCH), dim3(256), 0, stream, q, k, v, out);
    }
}

// Round 4
// 78.954 us; speedup vs baseline: 4.5483x; 1.1304x over previous
//
#include <hip/hip_runtime.h>
#include <hip/hip_bf16.h>

#define BATCH 16
#define SEQ   2048
#define DK    128
#define NT    (SEQ / 64)            // 32 kv tiles
#define SC2   0.12751744f           // (1/sqrt(128)) * log2(e)
#define THRAW 90.5f                 // defer-max threshold in raw-score units (= 8/scale)

typedef __attribute__((ext_vector_type(8))) short short8v;
typedef __attribute__((ext_vector_type(4))) float float4v;

typedef const __attribute__((address_space(1))) unsigned int* gas_t;
typedef __attribute__((address_space(3))) unsigned int* las_t;

__device__ inline void gl_lds16(const void* g, void* l) {
    __builtin_amdgcn_global_load_lds((gas_t)g, (las_t)l, 16, 0, 0);
}

__device__ inline short f2bf(float f) {
    __hip_bfloat16 h = __float2bfloat16(f);
    unsigned short u;
    __builtin_memcpy(&u, &h, sizeof(u));
    return (short)u;
}

__device__ inline unsigned cvt_pk_bf16(float a, float b) {
    unsigned r;
    asm("v_cvt_pk_bf16_f32 %0, %1, %2" : "=v"(r) : "v"(a), "v"(b));
    return r;   // lo = bf16(a), hi = bf16(b)
}

// ---------------- prepass: K fp32 -> bf16 (row-major) ----------------
__global__ __launch_bounds__(256)
void conv_k_kernel(const float* __restrict__ k, short* __restrict__ kb)
{
    size_t i = ((size_t)blockIdx.x * 256 + threadIdx.x) * 8;
    float4 a = *reinterpret_cast<const float4*>(k + i);
    float4 b = *reinterpret_cast<const float4*>(k + i + 4);
    short8v t;
    t[0] = f2bf(a.x); t[1] = f2bf(a.y); t[2] = f2bf(a.z); t[3] = f2bf(a.w);
    t[4] = f2bf(b.x); t[5] = f2bf(b.y); t[6] = f2bf(b.z); t[7] = f2bf(b.w);
    *reinterpret_cast<short8v*>(kb + i) = t;
}

// -------- prepass: V fp32 [b][s][d] -> bf16 Vt2 [b][d][pos] ----------
// Within each 64-kv tile, kv = 32*p2 + 16*h + 4*g + r is stored at
// pos = 32*p2 + 8*g + 4*h + r, so each PV B-fragment (p2,g) is one
// contiguous 16B unit: {V[32p2+4g+r]}r=0..3 ++ {V[32p2+16+4g+r]}r=0..3.
__global__ __launch_bounds__(256)
void transpose_v_kernel(const float* __restrict__ v, short* __restrict__ vt)
{
    __shared__ float tile[32][33];
    const int tx = threadIdx.x & 31;
    const int ty = threadIdx.x >> 5;              // 0..7
    const int b  = blockIdx.z;
    const int s0 = blockIdx.x * 32;
    const int d0 = blockIdx.y * 32;

    const float* vb = v + ((size_t)b * SEQ + s0) * DK + d0;
#pragma unroll
    for (int i = 0; i < 4; ++i) {
        int r = ty + 8 * i;
        tile[r][tx] = vb[(size_t)r * DK + tx];
    }
    __syncthreads();

    const int s   = s0 + tx;
    const int t   = s >> 6;
    const int kvl = s & 63;
    const int pos = ((kvl >> 5) << 5) | (((kvl >> 2) & 3) << 3) | (((kvl >> 4) & 1) << 2) | (kvl & 3);
    const size_t col = (size_t)(t << 6) + pos;

    short* vtb = vt + ((size_t)b * DK + d0) * SEQ;
#pragma unroll
    for (int i = 0; i < 4; ++i) {
        int r = ty + 8 * i;                       // d offset
        vtb[(size_t)r * SEQ + col] = f2bf(tile[tx][r]);
    }
}

// ---------------- main: flash attention, 2-phase pipelined ------------
// Block = 256 thr = 4 waves, each wave = 16 q rows (block = 64 q rows).
// All waves share K/V tiles (KVBLK=64) in double-buffered LDS (2 x 32KB).
// Pipeline per tile: STAGE(t+1 -> buf^1) issued BEFORE compute(t from buf);
// one __syncthreads() (drains vmcnt+lgkmcnt) per tile.
// LDS XOR-swizzle: linear dest + inverse-swizzled global src + swizzled read
// (byte ^= (row&7)<<4, 16B granule).  QK^T swapped: s[sub] lane holds
// S^T[kv=sub*16+4*grp+r][q=lane&15].  PV: pf[p2] slots j <-> kv =
// 32p2+16*(j>>2)+4*grp+(j&3); B frag = ONE b128 from interleaved V tile.
__global__ __launch_bounds__(256)
void attn_fwd_v4(const float* __restrict__ q,
                 const short* __restrict__ kb,
                 const short* __restrict__ vt,
                 float* __restrict__ out)
{
    __shared__ __align__(16) char lds[65536];   // [buf][K 16KB | V 16KB]

    const int tid  = threadIdx.x;
    const int lane = tid & 63;
    const int wave = tid >> 6;         // 0..3
    const int b    = blockIdx.y;
    const int q0   = blockIdx.x * 64 + wave * 16;

    const int row = lane & 15;
    const int grp = lane >> 4;
    const int swz = (row & 7) << 4;

    // ---- Q fragments (fp32 -> bf16, once) ----
    const float* qb = q + ((size_t)b * SEQ + q0) * DK;
    short8v qf[4];
#pragma unroll
    for (int c = 0; c < 4; ++c) {
        const float* p = qb + row * DK + c * 32 + grp * 8;
        float4 x = *reinterpret_cast<const float4*>(p);
        float4 y = *reinterpret_cast<const float4*>(p + 4);
        union { unsigned u[4]; short8v v; } pk;
        pk.u[0] = cvt_pk_bf16(x.x, x.y);
        pk.u[1] = cvt_pk_bf16(x.z, x.w);
        pk.u[2] = cvt_pk_bf16(y.x, y.y);
        pk.u[3] = cvt_pk_bf16(y.z, y.w);
        qf[c] = pk.v;
    }

    const char* kB = (const char*)(kb + (size_t)b * SEQ * DK);   // 256B rows
    const char* vB = (const char*)(vt + (size_t)b * DK * SEQ);   // 4096B rows

    // per-lane staging source sub-offsets
    const int kSrcCol = (lane & 15) << 4;   // byte col in 256B K row
    const int vSrcCol = (lane & 7) << 4;    // byte col in 128B V tile-slice

    float m_run = -1e30f;
    float l_run = 0.0f;
    float4v o[8];
#pragma unroll
    for (int i = 0; i < 8; ++i) { o[i][0] = 0.f; o[i][1] = 0.f; o[i][2] = 0.f; o[i][3] = 0.f; }

    // ---- staging: wave w stages K chunks 4w..4w+3 and V chunks 4w..4w+3 ----
    auto STAGE = [&](int bufsel, int t) {
        char* Kd = lds + bufsel * 32768;
        char* Vd = Kd + 16384;
        const char* ksrc = kB + (size_t)t * 64 * 256;     // K rows kv0..kv0+63
        const char* vsrc = vB + (size_t)t * 128;          // 128B slice per d row
#pragma unroll
        for (int i = 0; i < 4; ++i) {
            const int c  = wave * 4 + i;
            const int kr = 4 * c + (lane >> 4);           // K row 0..63
            gl_lds16(ksrc + (size_t)kr * 256 + (kSrcCol ^ ((kr & 7) << 4)),
                     Kd + c * 1024);
            const int vd = 8 * c + (lane >> 3);           // V d-row 0..127
            gl_lds16(vsrc + (size_t)vd * 4096 + (vSrcCol ^ ((vd & 7) << 4)),
                     Vd + c * 1024);
        }
    };

    STAGE(0, 0);
    __syncthreads();

    int buf = 0;
    for (int t = 0; t < NT; ++t) {
        if (t + 1 < NT) STAGE(buf ^ 1, t + 1);

        const char* Kl = lds + buf * 32768;
        const char* Vl = Kl + 16384;

        // ---- QK^T: 4 subtiles of 16 kv ----
        float4v s[4];
        __builtin_amdgcn_s_setprio(1);
#pragma unroll
        for (int sub = 0; sub < 4; ++sub) {
            s[sub][0] = 0.f; s[sub][1] = 0.f; s[sub][2] = 0.f; s[sub][3] = 0.f;
            const char* kr = Kl + (sub * 16 + row) * 256;
#pragma unroll
            for (int c = 0; c < 4; ++c) {
                short8v kf = *reinterpret_cast<const short8v*>(kr + (((c << 6) | (grp << 4)) ^ swz));
                s[sub] = __builtin_amdgcn_mfma_f32_16x16x32_bf16(kf, qf[c], s[sub], 0, 0, 0);
            }
        }
        __builtin_amdgcn_s_setprio(0);

        // ---- online softmax (raw-score domain; defer-max, THR = e^8) ----
        float p[16];
#pragma unroll
        for (int sub = 0; sub < 4; ++sub)
#pragma unroll
            for (int r = 0; r < 4; ++r) p[sub * 4 + r] = s[sub][r];

        float mx = p[0];
#pragma unroll
        for (int i = 1; i < 16; ++i) mx = fmaxf(mx, p[i]);
        mx = fmaxf(mx, __shfl_xor(mx, 16));
        mx = fmaxf(mx, __shfl_xor(mx, 32));

        if (!__all(mx <= m_run + THRAW)) {
            const float mnew  = fmaxf(m_run, mx);
            const float alpha = exp2f((m_run - mnew) * SC2);
            l_run *= alpha;
            m_run = mnew;
            float aq[4];
#pragma unroll
            for (int r = 0; r < 4; ++r) aq[r] = __shfl(alpha, grp * 4 + r);
#pragma unroll
            for (int dblk = 0; dblk < 8; ++dblk)
#pragma unroll
                for (int r = 0; r < 4; ++r) o[dblk][r] *= aq[r];
        }

        float tsum = 0.f;
#pragma unroll
        for (int i = 0; i < 16; ++i) { p[i] = exp2f((p[i] - m_run) * SC2); tsum += p[i]; }
        tsum += __shfl_xor(tsum, 16);
        tsum += __shfl_xor(tsum, 32);
        l_run += tsum;

        // ---- P -> bf16 fragments (cvt_pk) ----
        short8v pf[2];
#pragma unroll
        for (int p2 = 0; p2 < 2; ++p2) {
            union { unsigned u[4]; short8v v; } pk;
            pk.u[0] = cvt_pk_bf16(p[8 * p2 + 0], p[8 * p2 + 1]);
            pk.u[1] = cvt_pk_bf16(p[8 * p2 + 2], p[8 * p2 + 3]);
            pk.u[2] = cvt_pk_bf16(p[8 * p2 + 4], p[8 * p2 + 5]);
            pk.u[3] = cvt_pk_bf16(p[8 * p2 + 6], p[8 * p2 + 7]);
            pf[p2] = pk.v;
        }

        // ---- PV: B frag = one b128 from interleaved V tile ----
        __builtin_amdgcn_s_setprio(1);
#pragma unroll
        for (int dblk = 0; dblk < 8; ++dblk) {
            const char* vr = Vl + (dblk * 16 + row) * 128;
#pragma unroll
            for (int p2 = 0; p2 < 2; ++p2) {
                short8v vf = *reinterpret_cast<const short8v*>(vr + ((((p2 << 2) | grp) << 4) ^ swz));
                o[dblk] = __builtin_amdgcn_mfma_f32_16x16x32_bf16(pf[p2], vf, o[dblk], 0, 0, 0);
            }
        }
        __builtin_amdgcn_s_setprio(0);

        __syncthreads();       // drains staged loads (vmcnt 0) + LDS reads
        buf ^= 1;
    }

    // ---- epilogue: divide by l, write fp32 ----
    const float linv = 1.0f / l_run;
    float liq[4];
#pragma unroll
    for (int r = 0; r < 4; ++r) liq[r] = __shfl(linv, grp * 4 + r);

    float* ob = out + ((size_t)b * SEQ + q0) * DK;
#pragma unroll
    for (int dblk = 0; dblk < 8; ++dblk)
#pragma unroll
        for (int r = 0; r < 4; ++r)
            ob[(size_t)(grp * 4 + r) * DK + dblk * 16 + row] = o[dblk][r] * liq[r];
}

// ---------------- fallback (round-1 kernel) if ws too small -----------
__global__ __launch_bounds__(256)
void attn_fwd_slow(const float* __restrict__ q,
                   const float* __restrict__ k,
                   const float* __restrict__ v,
                   float* __restrict__ out)
{
    const int lane = threadIdx.x & 63;
    const int wave = threadIdx.x >> 6;
    const int b    = blockIdx.y;
    const int q0   = blockIdx.x * 64 + wave * 16;
    const int row = lane & 15;
    const int grp = lane >> 4;

    const float* qb = q + ((size_t)b * SEQ + q0) * DK;
    const float* kbp = k + (size_t)b * SEQ * DK;
    const float* vbp = v + (size_t)b * SEQ * DK;

    short8v qf[4];
#pragma unroll
    for (int c = 0; c < 4; ++c) {
        const float* p = qb + row * DK + c * 32 + grp * 8;
        float4 x = *reinterpret_cast<const float4*>(p);
        float4 y = *reinterpret_cast<const float4*>(p + 4);
        short8v t;
        t[0] = f2bf(x.x); t[1] = f2bf(x.y); t[2] = f2bf(x.z); t[3] = f2bf(x.w);
        t[4] = f2bf(y.x); t[5] = f2bf(y.y); t[6] = f2bf(y.z); t[7] = f2bf(y.w);
        qf[c] = t;
    }

    float m_run = -1e30f, l_run = 0.0f;
    float4v o[8];
#pragma unroll
    for (int i = 0; i < 8; ++i) { o[i][0]=0.f; o[i][1]=0.f; o[i][2]=0.f; o[i][3]=0.f; }
    const float scale = 0.08838834764831845f;

    for (int kv0 = 0; kv0 < SEQ; kv0 += 16) {
        short8v kf[4];
        const float* kp0 = kbp + (size_t)(kv0 + row) * DK + grp * 8;
#pragma unroll
        for (int c = 0; c < 4; ++c) {
            const float* p = kp0 + c * 32;
            float4 x = *reinterpret_cast<const float4*>(p);
            float4 y = *reinterpret_cast<const float4*>(p + 4);
            short8v t;
            t[0] = f2bf(x.x); t[1] = f2bf(x.y); t[2] = f2bf(x.z); t[3] = f2bf(x.w);
            t[4] = f2bf(y.x); t[5] = f2bf(y.y); t[6] = f2bf(y.z); t[7] = f2bf(y.w);
            kf[c] = t;
        }
        short8v vf[8];
#pragma unroll
        for (int dblk = 0; dblk < 8; ++dblk) {
            const float* p = vbp + (size_t)(kv0 + 4 * grp) * DK + dblk * 16 + row;
            short b0 = f2bf(p[0]);
            short b1 = f2bf(p[DK]);
            short b2 = f2bf(p[2 * DK]);
            short b3 = f2bf(p[3 * DK]);
            short8v t;
            t[0]=b0; t[1]=b1; t[2]=b2; t[3]=b3; t[4]=b0; t[5]=b1; t[6]=b2; t[7]=b3;
            vf[dblk] = t;
        }
        float4v s; s[0]=0.f; s[1]=0.f; s[2]=0.f; s[3]=0.f;
#pragma unroll
        for (int c = 0; c < 4; ++c)
            s = __builtin_amdgcn_mfma_f32_16x16x32_bf16(kf[c], qf[c], s, 0, 0, 0);

        float sv[4]; float tmax = -1e30f;
#pragma unroll
        for (int r = 0; r < 4; ++r) { sv[r] = s[r] * scale; tmax = fmaxf(tmax, sv[r]); }
        tmax = fmaxf(tmax, __shfl_xor(tmax, 16));
        tmax = fmaxf(tmax, __shfl_xor(tmax, 32));
        const float mnew = fmaxf(m_run, tmax);
        float pr[4]; float tsum = 0.f;
#pragma unroll
        for (int r = 0; r < 4; ++r) { pr[r] = __expf(sv[r] - mnew); tsum += pr[r]; }
        tsum += __shfl_xor(tsum, 16);
        tsum += __shfl_xor(tsum, 32);
        const float alpha = __expf(m_run - mnew);
        l_run = l_run * alpha + tsum;
        m_run = mnew;
        float aq[4];
#pragma unroll
        for (int r = 0; r < 4; ++r) aq[r] = __shfl(alpha, grp * 4 + r);
#pragma unroll
        for (int dblk = 0; dblk < 8; ++dblk)
#pragma unroll
            for (int r = 0; r < 4; ++r) o[dblk][r] *= aq[r];

        short8v pf;
        pf[0]=f2bf(pr[0]); pf[1]=f2bf(pr[1]); pf[2]=f2bf(pr[2]); pf[3]=f2bf(pr[3]);
        pf[4]=0; pf[5]=0; pf[6]=0; pf[7]=0;
#pragma unroll
        for (int dblk = 0; dblk < 8; ++dblk)
            o[dblk] = __builtin_amdgcn_mfma_f32_16x16x32_bf16(pf, vf[dblk], o[dblk], 0, 0, 0);
    }

    const float linv = 1.0f / l_run;
    float li[4];
#pragma unroll
    for (int r = 0; r < 4; ++r) li[r] = __shfl(linv, grp * 4 + r);
    float* ob = out + ((size_t)b * SEQ + q0) * DK;
#pragma unroll
    for (int dblk = 0; dblk < 8; ++dblk)
#pragma unroll
        for (int r = 0; r < 4; ++r)
            ob[(size_t)(grp * 4 + r) * DK + dblk * 16 + row] = o[dblk][r] * li[r];
}

extern "C" void kernel_launch(void* const* d_in, const int* in_sizes, int n_in,
                              void* d_out, int out_size, void* d_ws, size_t ws_size,
                              hipStream_t stream) {
    const float* q = (const float*)d_in[0];
    const float* k = (const float*)d_in[1];
    const float* v = (const float*)d_in[2];
    float* out = (float*)d_out;

    const size_t kb_bytes = (size_t)BATCH * SEQ * DK * sizeof(short);
    const size_t need = 2 * kb_bytes;

    if (ws_size >= need) {
        short* kb = (short*)d_ws;
        short* vt = (short*)((char*)d_ws + kb_bytes);
        hipLaunchKernelGGL(conv_k_kernel, dim3(2048), dim3(256), 0, stream, k, kb);
        hipLaunchKernelGGL(transpose_v_kernel, dim3(SEQ / 32, DK / 32, BATCH), dim3(256), 0, stream, v, vt);
        hipLaunchKernelGGL(attn_fwd_v4, dim3(SEQ / 64, BATCH), dim3(256), 0, stream, q, kb, vt, out);
    } else {
        hipLaunchKernelGGL(attn_fwd_slow, dim3(SEQ / 64, BATCH), dim3(256), 0, stream, q, k, v, out);
    }
}

// Round 5
// 74.021 us; speedup vs baseline: 4.8515x; 1.0667x over previous
//
#include <hip/hip_runtime.h>
#include <hip/hip_bf16.h>

#define BATCH 16
#define SEQ   2048
#define DK    128
#define NT    (SEQ / 2 / 32)        // 32 kv steps per half (KVBLK=32)
#define SC2   0.12751744f           // (1/sqrt(128)) * log2(e)  -- folded into K prepass
#define THRL2 11.541560f            // defer-max threshold in log2-score units (= 8*log2e)

typedef __attribute__((ext_vector_type(8))) short short8v;
typedef __attribute__((ext_vector_type(4))) float float4v;

typedef const __attribute__((address_space(1))) unsigned int* gas_t;
typedef __attribute__((address_space(3))) unsigned int* las_t;

__device__ inline void gl_lds16(const void* g, void* l) {
    __builtin_amdgcn_global_load_lds((gas_t)g, (las_t)l, 16, 0, 0);
}

__device__ inline short f2bf(float f) {
    __hip_bfloat16 h = __float2bfloat16(f);
    unsigned short u;
    __builtin_memcpy(&u, &h, sizeof(u));
    return (short)u;
}

__device__ inline unsigned cvt_pk_bf16(float a, float b) {
    unsigned r;
    asm("v_cvt_pk_bf16_f32 %0, %1, %2" : "=v"(r) : "v"(a), "v"(b));
    return r;   // lo = bf16(a), hi = bf16(b)
}

// -------- prepass: K fp32 -> bf16 * (scale*log2e)  (row-major) --------
// Scores computed against this K are directly in log2-domain.
__global__ __launch_bounds__(256)
void conv_k_kernel(const float* __restrict__ k, short* __restrict__ kb)
{
    size_t i = ((size_t)blockIdx.x * 256 + threadIdx.x) * 8;
    float4 a = *reinterpret_cast<const float4*>(k + i);
    float4 b = *reinterpret_cast<const float4*>(k + i + 4);
    short8v t;
    t[0] = f2bf(a.x * SC2); t[1] = f2bf(a.y * SC2); t[2] = f2bf(a.z * SC2); t[3] = f2bf(a.w * SC2);
    t[4] = f2bf(b.x * SC2); t[5] = f2bf(b.y * SC2); t[6] = f2bf(b.z * SC2); t[7] = f2bf(b.w * SC2);
    *reinterpret_cast<short8v*>(kb + i) = t;
}

// -------- prepass: V fp32 [b][s][d] -> bf16 Vt2 [b][d][pos] -----------
// Within each 32-kv tile, kv = 16*h' + 4*g + r stored at pos = 8*g + 4*h' + r,
// so each PV B-fragment (grp g) is one contiguous 16B unit.
__global__ __launch_bounds__(256)
void transpose_v_kernel(const float* __restrict__ v, short* __restrict__ vt)
{
    __shared__ float tile[32][33];
    const int tx = threadIdx.x & 31;
    const int ty = threadIdx.x >> 5;              // 0..7
    const int b  = blockIdx.z;
    const int s0 = blockIdx.x * 32;
    const int d0 = blockIdx.y * 32;

    const float* vb = v + ((size_t)b * SEQ + s0) * DK + d0;
#pragma unroll
    for (int i = 0; i < 4; ++i) {
        int r = ty + 8 * i;
        tile[r][tx] = vb[(size_t)r * DK + tx];
    }
    __syncthreads();

    const int s   = s0 + tx;
    const int kvl = s & 31;
    const int pos = (((kvl >> 2) & 3) << 3) | (((kvl >> 4) & 1) << 2) | (kvl & 3);
    const size_t col = (size_t)(s & ~31) | pos;

    short* vtb = vt + ((size_t)b * DK + d0) * SEQ;
#pragma unroll
    for (int i = 0; i < 4; ++i) {
        int r = ty + 8 * i;                       // d offset
        vtb[(size_t)r * SEQ + col] = f2bf(tile[tx][r]);
    }
}

// ---------------- main: flash attention, 8-wave split-kv --------------
// Block = 512 thr = 8 waves: qt = wave&3 (16 q rows), h = wave>>2 (kv half).
// Grid (32,16) -> 4096 waves = 16/CU = 4 waves/SIMD (latency hiding).
// KVBLK=32 per half, double-buffered: LDS = 2buf x 2half x (K 8KB + V 8KB).
// 2-phase pipeline: STAGE(t+1 -> buf^1) BEFORE compute(t); 1 barrier/step.
// K swizzle (256B rows): byte ^= (row&7)<<4. V swizzle (64B rows):
// byte ^= ((row>>1)&3)<<4. Both 2-way bank aliasing = free.
// QK^T swapped: s[sub] lane holds S^T[kv=sub*16+4*grp+r][q=lane&15].
// PV: pf slots j <-> kv = 16*(j>>2)+4*grp+(j&3); B frag = one b128.
__global__ __launch_bounds__(512)
void attn_fwd_v5(const float* __restrict__ q,
                 const short* __restrict__ kb,
                 const short* __restrict__ vt,
                 float* __restrict__ out)
{
    __shared__ __align__(16) char lds[65536];

    const int tid  = threadIdx.x;
    const int lane = tid & 63;
    const int wave = tid >> 6;         // 0..7
    const int qt   = wave & 3;
    const int h    = wave >> 2;        // kv half
    const int b    = blockIdx.y;
    const int q0   = blockIdx.x * 64 + qt * 16;

    const int row  = lane & 15;
    const int grp  = lane >> 4;
    const int kswz = (row & 7) << 4;          // K read swizzle (kr&7 == row&7)
    const int vswz = ((row >> 1) & 3) << 4;   // V read swizzle ((row'>>1)&3 inv. to dblk)

    // ---- Q fragments (fp32 -> bf16, once; unscaled -- K carries scale) ----
    const float* qb = q + ((size_t)b * SEQ + q0) * DK;
    short8v qf[4];
#pragma unroll
    for (int c = 0; c < 4; ++c) {
        const float* p = qb + row * DK + c * 32 + grp * 8;
        float4 x = *reinterpret_cast<const float4*>(p);
        float4 y = *reinterpret_cast<const float4*>(p + 4);
        union { unsigned u[4]; short8v v; } pk;
        pk.u[0] = cvt_pk_bf16(x.x, x.y);
        pk.u[1] = cvt_pk_bf16(x.z, x.w);
        pk.u[2] = cvt_pk_bf16(y.x, y.y);
        pk.u[3] = cvt_pk_bf16(y.z, y.w);
        qf[c] = pk.v;
    }

    const char* kB = (const char*)(kb + (size_t)b * SEQ * DK);   // 256B rows
    const char* vB = (const char*)(vt + (size_t)b * DK * SEQ);   // 4096B rows

    // ---- per-wave staging chunks: c = wave*4+i over 32 chunks/step ----
    // c in [0,16): K, half hh=c>>3, sub-chunk cc=c&7 (4 kv rows each)
    // c in [16,32): V, half hh=(c>>3)&1, cc=c&7 (16 d rows each)
    const char* src0[4];     // per-i source base (t=0)
    int         sstr[4];     // per-t source stride
    int         dsto[4];     // dest offset within buffer
#pragma unroll
    for (int i = 0; i < 4; ++i) {
        const int c = wave * 4 + i;
        if (c < 16) {
            const int hh = c >> 3, cc = c & 7;
            const int kr = 4 * cc + (lane >> 4);            // kv row in 32-tile
            src0[i] = kB + (size_t)(hh * 1024 + kr) * 256
                         + (((lane & 15) << 4) ^ ((kr & 7) << 4));
            sstr[i] = 32 * 256;                             // 32 kv per step
            dsto[i] = hh * 8192 + cc * 1024;
        } else {
            const int hh = (c >> 3) & 1, cc = c & 7;
            const int vd = 16 * cc + (lane >> 2);           // d row 0..127
            src0[i] = vB + (size_t)vd * 4096 + hh * 2048
                         + (((lane & 3) << 4) ^ (((lane >> 3) & 3) << 4));
            sstr[i] = 32 * 2;                               // 64B per step
            dsto[i] = 16384 + hh * 8192 + cc * 1024;
        }
    }

    float m_run = -1e30f;
    float l_run = 0.0f;
    float4v o[8];
#pragma unroll
    for (int i = 0; i < 8; ++i) { o[i][0] = 0.f; o[i][1] = 0.f; o[i][2] = 0.f; o[i][3] = 0.f; }

    auto STAGE = [&](int bufsel, int t) {
        char* base = lds + bufsel * 32768;
#pragma unroll
        for (int i = 0; i < 4; ++i)
            gl_lds16(src0[i] + (size_t)t * sstr[i], base + dsto[i]);
    };

    STAGE(0, 0);
    __syncthreads();

    int buf = 0;
    for (int t = 0; t < NT; ++t) {
        if (t + 1 < NT) STAGE(buf ^ 1, t + 1);

        const char* Kl = lds + buf * 32768 + h * 8192;
        const char* Vl = lds + buf * 32768 + 16384 + h * 8192;

        // ---- QK^T: 2 subtiles of 16 kv ----
        float4v s[2];
        __builtin_amdgcn_s_setprio(1);
#pragma unroll
        for (int sub = 0; sub < 2; ++sub) {
            s[sub][0] = 0.f; s[sub][1] = 0.f; s[sub][2] = 0.f; s[sub][3] = 0.f;
            const char* kr = Kl + (sub * 16 + row) * 256;
#pragma unroll
            for (int c = 0; c < 4; ++c) {
                short8v kf = *reinterpret_cast<const short8v*>(kr + (((c << 6) | (grp << 4)) ^ kswz));
                s[sub] = __builtin_amdgcn_mfma_f32_16x16x32_bf16(kf, qf[c], s[sub], 0, 0, 0);
            }
        }
        __builtin_amdgcn_s_setprio(0);

        // ---- online softmax (log2-domain scores; defer-max) ----
        float mx = fmaxf(fmaxf(fmaxf(s[0][0], s[0][1]), fmaxf(s[0][2], s[0][3])),
                         fmaxf(fmaxf(s[1][0], s[1][1]), fmaxf(s[1][2], s[1][3])));
        mx = fmaxf(mx, __shfl_xor(mx, 16));
        mx = fmaxf(mx, __shfl_xor(mx, 32));

        if (!__all(mx <= m_run + THRL2)) {
            const float mnew  = fmaxf(m_run, mx);
            const float alpha = exp2f(m_run - mnew);
            l_run *= alpha;
            m_run = mnew;
            float aq[4];
#pragma unroll
            for (int r = 0; r < 4; ++r) aq[r] = __shfl(alpha, grp * 4 + r);
#pragma unroll
            for (int dblk = 0; dblk < 8; ++dblk)
#pragma unroll
                for (int r = 0; r < 4; ++r) o[dblk][r] *= aq[r];
        }

        float tsum = 0.f;
#pragma unroll
        for (int sub = 0; sub < 2; ++sub)
#pragma unroll
            for (int r = 0; r < 4; ++r) {
                const float e = exp2f(s[sub][r] - m_run);
                s[sub][r] = e;
                tsum += e;
            }
        tsum += __shfl_xor(tsum, 16);
        tsum += __shfl_xor(tsum, 32);
        l_run += tsum;

        // ---- P -> bf16 fragment (one short8v covers the 32 kv) ----
        union { unsigned u[4]; short8v v; } pk;
        pk.u[0] = cvt_pk_bf16(s[0][0], s[0][1]);
        pk.u[1] = cvt_pk_bf16(s[0][2], s[0][3]);
        pk.u[2] = cvt_pk_bf16(s[1][0], s[1][1]);
        pk.u[3] = cvt_pk_bf16(s[1][2], s[1][3]);
        const short8v pf = pk.v;

        // ---- PV: B frag = one b128 from interleaved V tile ----
        __builtin_amdgcn_s_setprio(1);
#pragma unroll
        for (int dblk = 0; dblk < 8; ++dblk) {
            const short8v vf = *reinterpret_cast<const short8v*>(
                Vl + (dblk * 16 + row) * 64 + ((grp << 4) ^ vswz));
            o[dblk] = __builtin_amdgcn_mfma_f32_16x16x32_bf16(pf, vf, o[dblk], 0, 0, 0);
        }
        __builtin_amdgcn_s_setprio(0);

        __syncthreads();       // drains staged loads + LDS reads
        buf ^= 1;
    }

    // ---- merge halves via LDS (aliases K/V buffers; all compute done) ----
    float* smO = (float*)lds;                 // [4][16][132] = 33792 B
    float* smM = (float*)(lds + 33792);       // [4][16]
    float* smL = (float*)(lds + 34048);       // [4][16]

    if (h == 1) {
        smM[qt * 16 + row] = m_run;
        smL[qt * 16 + row] = l_run;
#pragma unroll
        for (int dblk = 0; dblk < 8; ++dblk)
#pragma unroll
            for (int r = 0; r < 4; ++r)
                smO[(qt * 16 + grp * 4 + r) * 132 + dblk * 16 + row] = o[dblk][r];
    }
    __syncthreads();
    if (h == 0) {
        const float m1 = smM[qt * 16 + row];
        const float l1 = smL[qt * 16 + row];
        const float mf = fmaxf(m_run, m1);
        const float a0 = exp2f(m_run - mf);
        const float a1 = exp2f(m1 - mf);
        const float lf = l_run * a0 + l1 * a1;
        const float li = 1.0f / lf;

        float a0q[4], a1q[4], liq[4];
#pragma unroll
        for (int r = 0; r < 4; ++r) {
            a0q[r] = __shfl(a0, grp * 4 + r);
            a1q[r] = __shfl(a1, grp * 4 + r);
            liq[r] = __shfl(li, grp * 4 + r);
        }

        float* ob = out + ((size_t)b * SEQ + q0) * DK;
#pragma unroll
        for (int dblk = 0; dblk < 8; ++dblk)
#pragma unroll
            for (int r = 0; r < 4; ++r) {
                float val = (o[dblk][r] * a0q[r]
                             + smO[(qt * 16 + grp * 4 + r) * 132 + dblk * 16 + row] * a1q[r]) * liq[r];
                ob[(size_t)(grp * 4 + r) * DK + dblk * 16 + row] = val;
            }
    }
}

// ---------------- fallback (round-1 kernel) if ws too small -----------
__global__ __launch_bounds__(256)
void attn_fwd_slow(const float* __restrict__ q,
                   const float* __restrict__ k,
                   const float* __restrict__ v,
                   float* __restrict__ out)
{
    const int lane = threadIdx.x & 63;
    const int wave = threadIdx.x >> 6;
    const int b    = blockIdx.y;
    const int q0   = blockIdx.x * 64 + wave * 16;
    const int row = lane & 15;
    const int grp = lane >> 4;

    const float* qb = q + ((size_t)b * SEQ + q0) * DK;
    const float* kbp = k + (size_t)b * SEQ * DK;
    const float* vbp = v + (size_t)b * SEQ * DK;

    short8v qf[4];
#pragma unroll
    for (int c = 0; c < 4; ++c) {
        const float* p = qb + row * DK + c * 32 + grp * 8;
        float4 x = *reinterpret_cast<const float4*>(p);
        float4 y = *reinterpret_cast<const float4*>(p + 4);
        short8v t;
        t[0] = f2bf(x.x); t[1] = f2bf(x.y); t[2] = f2bf(x.z); t[3] = f2bf(x.w);
        t[4] = f2bf(y.x); t[5] = f2bf(y.y); t[6] = f2bf(y.z); t[7] = f2bf(y.w);
        qf[c] = t;
    }

    float m_run = -1e30f, l_run = 0.0f;
    float4v o[8];
#pragma unroll
    for (int i = 0; i < 8; ++i) { o[i][0]=0.f; o[i][1]=0.f; o[i][2]=0.f; o[i][3]=0.f; }
    const float scale = 0.08838834764831845f;

    for (int kv0 = 0; kv0 < SEQ; kv0 += 16) {
        short8v kf[4];
        const float* kp0 = kbp + (size_t)(kv0 + row) * DK + grp * 8;
#pragma unroll
        for (int c = 0; c < 4; ++c) {
            const float* p = kp0 + c * 32;
            float4 x = *reinterpret_cast<const float4*>(p);
            float4 y = *reinterpret_cast<const float4*>(p + 4);
            short8v t;
            t[0] = f2bf(x.x); t[1] = f2bf(x.y); t[2] = f2bf(x.z); t[3] = f2bf(x.w);
            t[4] = f2bf(y.x); t[5] = f2bf(y.y); t[6] = f2bf(y.z); t[7] = f2bf(y.w);
            kf[c] = t;
        }
        short8v vf[8];
#pragma unroll
        for (int dblk = 0; dblk < 8; ++dblk) {
            const float* p = vbp + (size_t)(kv0 + 4 * grp) * DK + dblk * 16 + row;
            short b0 = f2bf(p[0]);
            short b1 = f2bf(p[DK]);
            short b2 = f2bf(p[2 * DK]);
            short b3 = f2bf(p[3 * DK]);
            short8v t;
            t[0]=b0; t[1]=b1; t[2]=b2; t[3]=b3; t[4]=b0; t[5]=b1; t[6]=b2; t[7]=b3;
            vf[dblk] = t;
        }
        float4v s; s[0]=0.f; s[1]=0.f; s[2]=0.f; s[3]=0.f;
#pragma unroll
        for (int c = 0; c < 4; ++c)
            s = __builtin_amdgcn_mfma_f32_16x16x32_bf16(kf[c], qf[c], s, 0, 0, 0);

        float sv[4]; float tmax = -1e30f;
#pragma unroll
        for (int r = 0; r < 4; ++r) { sv[r] = s[r] * scale; tmax = fmaxf(tmax, sv[r]); }
        tmax = fmaxf(tmax, __shfl_xor(tmax, 16));
        tmax = fmaxf(tmax, __shfl_xor(tmax, 32));
        const float mnew = fmaxf(m_run, tmax);
        float pr[4]; float tsum = 0.f;
#pragma unroll
        for (int r = 0; r < 4; ++r) { pr[r] = __expf(sv[r] - mnew); tsum += pr[r]; }
        tsum += __shfl_xor(tsum, 16);
        tsum += __shfl_xor(tsum, 32);
        const float alpha = __expf(m_run - mnew);
        l_run = l_run * alpha + tsum;
        m_run = mnew;
        float aq[4];
#pragma unroll
        for (int r = 0; r < 4; ++r) aq[r] = __shfl(alpha, grp * 4 + r);
#pragma unroll
        for (int dblk = 0; dblk < 8; ++dblk)
#pragma unroll
            for (int r = 0; r < 4; ++r) o[dblk][r] *= aq[r];

        short8v pf;
        pf[0]=f2bf(pr[0]); pf[1]=f2bf(pr[1]); pf[2]=f2bf(pr[2]); pf[3]=f2bf(pr[3]);
        pf[4]=0; pf[5]=0; pf[6]=0; pf[7]=0;
#pragma unroll
        for (int dblk = 0; dblk < 8; ++dblk)
            o[dblk] = __builtin_amdgcn_mfma_f32_16x16x32_bf16(pf, vf[dblk], o[dblk], 0, 0, 0);
    }

    const float linv = 1.0f / l_run;
    float li[4];
#pragma unroll
    for (int r = 0; r < 4; ++r) li[r] = __shfl(linv, grp * 4 + r);
    float* ob = out + ((size_t)b * SEQ + q0) * DK;
#pragma unroll
    for (int dblk = 0; dblk < 8; ++dblk)
#pragma unroll
        for (int r = 0; r < 4; ++r)
            ob[(size_t)(grp * 4 + r) * DK + dblk * 16 + row] = o[dblk][r] * li[r];
}

extern "C" void kernel_launch(void* const* d_in, const int* in_sizes, int n_in,
                              void* d_out, int out_size, void* d_ws, size_t ws_size,
                              hipStream_t stream) {
    const float* q = (const float*)d_in[0];
    const float* k = (const float*)d_in[1];
    const float* v = (const float*)d_in[2];
    float* out = (float*)d_out;

    const size_t kb_bytes = (size_t)BATCH * SEQ * DK * sizeof(short);
    const size_t need = 2 * kb_bytes;

    if (ws_size >= need) {
        short* kb = (short*)d_ws;
        short* vt = (short*)((char*)d_ws + kb_bytes);
        hipLaunchKernelGGL(conv_k_kernel, dim3(2048), dim3(256), 0, stream, k, kb);
        hipLaunchKernelGGL(transpose_v_kernel, dim3(SEQ / 32, DK / 32, BATCH), dim3(256), 0, stream, v, vt);
        hipLaunchKernelGGL(attn_fwd_v5, dim3(SEQ / 64, BATCH), dim3(512), 0, stream, q, kb, vt, out);
    } else {
        hipLaunchKernelGGL(attn_fwd_slow, dim3(SEQ / 64, BATCH), dim3(256), 0, stream, q, k, v, out);
    }
}

// Round 6
// 64.623 us; speedup vs baseline: 5.5570x; 1.1454x over previous
//
#include <hip/hip_runtime.h>
#include <hip/hip_bf16.h>

#define BATCH 16
#define SEQ   2048
#define DK    128
#define NT    16                    // kv steps per half (KVBLK=64 over 1024)
#define SC2   0.12751744f           // (1/sqrt(128)) * log2(e) -- folded into K prepass
#define THRL2 11.541560f            // defer-max threshold (= 8*log2e)

typedef __attribute__((ext_vector_type(8)))  short short8v;
typedef __attribute__((ext_vector_type(4)))  float float4v;
typedef __attribute__((ext_vector_type(16))) float float16v;

typedef const __attribute__((address_space(1))) unsigned int* gas_t;
typedef __attribute__((address_space(3))) unsigned int* las_t;

__device__ inline void gl_lds16(const void* g, void* l) {
    __builtin_amdgcn_global_load_lds((gas_t)g, (las_t)l, 16, 0, 0);
}

__device__ inline short f2bf(float f) {
    __hip_bfloat16 h = __float2bfloat16(f);
    unsigned short u;
    __builtin_memcpy(&u, &h, sizeof(u));
    return (short)u;
}

__device__ inline unsigned cvt_pk_bf16(float a, float b) {
    unsigned r;
    asm("v_cvt_pk_bf16_f32 %0, %1, %2" : "=v"(r) : "v"(a), "v"(b));
    return r;   // lo = bf16(a), hi = bf16(b)
}

// -------- prepass: K fp32 -> bf16 * (scale*log2e)  (row-major) --------
__global__ __launch_bounds__(256)
void conv_k_kernel(const float* __restrict__ k, short* __restrict__ kb)
{
    size_t i = ((size_t)blockIdx.x * 256 + threadIdx.x) * 8;
    float4 a = *reinterpret_cast<const float4*>(k + i);
    float4 b = *reinterpret_cast<const float4*>(k + i + 4);
    short8v t;
    t[0] = f2bf(a.x * SC2); t[1] = f2bf(a.y * SC2); t[2] = f2bf(a.z * SC2); t[3] = f2bf(a.w * SC2);
    t[4] = f2bf(b.x * SC2); t[5] = f2bf(b.y * SC2); t[6] = f2bf(b.z * SC2); t[7] = f2bf(b.w * SC2);
    *reinterpret_cast<short8v*>(kb + i) = t;
}

// -------- prepass: V fp32 [b][s][d] -> bf16 Vt [b][d][col] ------------
// psi-interleave per 16-kv group: V[kv] stored at col = base16 | pos,
// pos = 8*((kv>>2)&1) + 4*((kv>>3)&1) + (kv&3), so each 32x32-MFMA PV
// A-fragment {p[r]} r=0..7 matches one contiguous 16B B-fragment unit.
__global__ __launch_bounds__(256)
void transpose_v_kernel(const float* __restrict__ v, short* __restrict__ vt)
{
    __shared__ float tile[32][33];
    const int tx = threadIdx.x & 31;
    const int ty = threadIdx.x >> 5;              // 0..7
    const int b  = blockIdx.z;
    const int s0 = blockIdx.x * 32;
    const int d0 = blockIdx.y * 32;

    const float* vb = v + ((size_t)b * SEQ + s0) * DK + d0;
#pragma unroll
    for (int i = 0; i < 4; ++i) {
        int r = ty + 8 * i;
        tile[r][tx] = vb[(size_t)r * DK + tx];
    }
    __syncthreads();

    const int s   = s0 + tx;
    const int kvl = s & 15;
    const int pos = (((kvl >> 2) & 1) << 3) | (((kvl >> 3) & 1) << 2) | (kvl & 3);
    const size_t col = (size_t)(s & ~15) | pos;

    short* vtb = vt + ((size_t)b * DK + d0) * SEQ;
#pragma unroll
    for (int i = 0; i < 4; ++i) {
        int r = ty + 8 * i;                       // d offset
        vtb[(size_t)r * SEQ + col] = f2bf(tile[tx][r]);
    }
}

// ---------------- main: flash attention, 32x32 MFMA -------------------
// Block = 512 thr = 8 waves: qt = wave&3 (32 q rows), h = wave>>2 (kv half).
// Grid (16,16) = 256 blocks = 1/CU; LDS 128 KB = 2buf x 2half x (K16K+V16K).
// 2-phase pipeline: STAGE(t+1 -> buf^1) issued BEFORE compute(t); 1 barrier.
// K tile [64 kv][256B], read swizzle unit ^= (row&15)  -> 16 slots, 4-way.
// V tile d-pair packed [64 R][256B], R = d>>1, slot w = ((d&1)<<3|u)^(R&15),
// u = 2g+hi (16B kv-unit, psi-ordered)                  -> 16 slots, 4-way.
// QK^T = mfma32(K, Q): lane q = lane&31 holds S^T rows crow(reg,hi) =
// (reg&3)+8*(reg>>2)+4*hi per 32-kv subtile.  PV = mfma32(P, V): pf[g] =
// packed p-regs (psi makes k-order match); O rows = crow(reg,hi).
__global__ __launch_bounds__(512, 2)
void attn_fwd_v6(const float* __restrict__ q,
                 const short* __restrict__ kb,
                 const short* __restrict__ vt,
                 float* __restrict__ out)
{
    __shared__ __align__(16) char lds[131072];

    const int tid  = threadIdx.x;
    const int lane = tid & 63;
    const int wave = tid >> 6;         // 0..7
    const int qt   = wave & 3;
    const int h    = wave >> 2;        // kv half
    const int b    = blockIdx.y;
    const int q0   = blockIdx.x * 128 + qt * 32;

    const int l31 = lane & 31;
    const int hi  = lane >> 5;

    // ---- Q fragments: qf[s] = Q[q0+l31][s*16 + hi*8 + 0..7] ----
    const float* qrow = q + ((size_t)b * SEQ + q0 + l31) * DK + hi * 8;
    short8v qf[8];
#pragma unroll
    for (int s = 0; s < 8; ++s) {
        float4 x = *reinterpret_cast<const float4*>(qrow + s * 16);
        float4 y = *reinterpret_cast<const float4*>(qrow + s * 16 + 4);
        union { unsigned u[4]; short8v v; } pk;
        pk.u[0] = cvt_pk_bf16(x.x, x.y);
        pk.u[1] = cvt_pk_bf16(x.z, x.w);
        pk.u[2] = cvt_pk_bf16(y.x, y.y);
        pk.u[3] = cvt_pk_bf16(y.z, y.w);
        qf[s] = pk.v;
    }

    // ---- staging setup: waves 0,1|4,5 -> K; waves 2,3|6,7 -> V ----
    const char* kB = (const char*)(kb + (size_t)b * SEQ * DK);   // 256B rows
    const char* vB = (const char*)(vt + (size_t)b * DK * SEQ);   // 4096B rows
    const int hkv = h * 1024;

    const char* src[8];
    int dstoff[8];
    long sstep;
    if (qt < 2) {
#pragma unroll
        for (int i = 0; i < 8; ++i) {
            const int kr = qt * 32 + i * 4 + (lane >> 4);        // kv row 0..63
            src[i] = kB + (size_t)(hkv + kr) * 256 + (((lane & 15) ^ (kr & 15)) << 4);
            dstoff[i] = h * 32768 + qt * 8192 + i * 1024;
        }
        sstep = 64 * 256;
    } else {
#pragma unroll
        for (int i = 0; i < 8; ++i) {
            const int R  = (qt - 2) * 32 + i * 4 + (lane >> 4);  // R row 0..63
            const int wx = (lane & 15) ^ (R & 15);
            const int d  = 2 * R + (wx >> 3);
            src[i] = vB + (size_t)d * (SEQ * 2) + (size_t)hkv * 2 + ((wx & 7) << 4);
            dstoff[i] = h * 32768 + 16384 + (qt - 2) * 8192 + i * 1024;
        }
        sstep = 64 * 2;
    }

    float m_run = -1e30f;
    float l_run = 0.0f;
    float16v o[4];
#pragma unroll
    for (int dblk = 0; dblk < 4; ++dblk)
#pragma unroll
        for (int i = 0; i < 16; ++i) o[dblk][i] = 0.f;

    auto STAGE = [&](int bufsel, int t) {
        char* base = lds + bufsel * 65536;
#pragma unroll
        for (int i = 0; i < 8; ++i)
            gl_lds16(src[i] + (size_t)t * sstep, base + dstoff[i]);
    };

    STAGE(0, 0);
    __syncthreads();

    int buf = 0;
    for (int t = 0; t < NT; ++t) {
        if (t + 1 < NT) STAGE(buf ^ 1, t + 1);

        const char* Kl = lds + buf * 65536 + h * 32768;
        const char* Vl = Kl + 16384;
        const char* ka = Kl + l31 * 256;

        // ---- QK^T: 2 subtiles of 32 kv over D=128 ----
        float16v sa[2];
#pragma unroll
        for (int i = 0; i < 16; ++i) { sa[0][i] = 0.f; sa[1][i] = 0.f; }
        __builtin_amdgcn_s_setprio(1);
#pragma unroll
        for (int s = 0; s < 8; ++s) {
            const int un = ((2 * s + hi) ^ (l31 & 15)) << 4;
            short8v kf0 = *reinterpret_cast<const short8v*>(ka + un);
            short8v kf1 = *reinterpret_cast<const short8v*>(ka + 8192 + un);
            sa[0] = __builtin_amdgcn_mfma_f32_32x32x16_bf16(kf0, qf[s], sa[0], 0, 0, 0);
            sa[1] = __builtin_amdgcn_mfma_f32_32x32x16_bf16(kf1, qf[s], sa[1], 0, 0, 0);
        }
        __builtin_amdgcn_s_setprio(0);

        // ---- online softmax (log2-domain; defer-max) ----
        float mx = sa[0][0];
#pragma unroll
        for (int i = 1; i < 16; ++i) mx = fmaxf(mx, sa[0][i]);
#pragma unroll
        for (int i = 0; i < 16; ++i) mx = fmaxf(mx, sa[1][i]);
        mx = fmaxf(mx, __shfl_xor(mx, 32));

        if (!__all(mx <= m_run + THRL2)) {
            const float mnew  = fmaxf(m_run, mx);
            const float alpha = exp2f(m_run - mnew);
            l_run *= alpha;
            m_run = mnew;
            float aq[16];
#pragma unroll
            for (int reg = 0; reg < 16; ++reg)
                aq[reg] = __shfl(alpha, (reg & 3) + 8 * (reg >> 2) + 4 * hi);
#pragma unroll
            for (int dblk = 0; dblk < 4; ++dblk)
#pragma unroll
                for (int reg = 0; reg < 16; ++reg) o[dblk][reg] *= aq[reg];
        }

        float ts = 0.f;
#pragma unroll
        for (int sub = 0; sub < 2; ++sub)
#pragma unroll
            for (int i = 0; i < 16; ++i) {
                const float e = exp2f(sa[sub][i] - m_run);
                sa[sub][i] = e;
                ts += e;
            }
        ts += __shfl_xor(ts, 32);
        l_run += ts;

        // ---- P -> bf16 A-fragments (psi-order: pf[g] = packed p-regs) ----
        short8v pf[4];
#pragma unroll
        for (int g = 0; g < 4; ++g) {
            const int sub = g >> 1, r0 = (g & 1) * 8;
            union { unsigned u[4]; short8v v; } pk;
            pk.u[0] = cvt_pk_bf16(sa[sub][r0 + 0], sa[sub][r0 + 1]);
            pk.u[1] = cvt_pk_bf16(sa[sub][r0 + 2], sa[sub][r0 + 3]);
            pk.u[2] = cvt_pk_bf16(sa[sub][r0 + 4], sa[sub][r0 + 5]);
            pk.u[3] = cvt_pk_bf16(sa[sub][r0 + 6], sa[sub][r0 + 7]);
            pf[g] = pk.v;
        }

        // ---- PV: B frag = one b128 from d-pair-packed V tile ----
        __builtin_amdgcn_s_setprio(1);
#pragma unroll
        for (int dblk = 0; dblk < 4; ++dblk) {
            const int R  = dblk * 16 + (l31 >> 1);
            const char* vr = Vl + R * 256;
            const int dh = (l31 & 1) << 3;
#pragma unroll
            for (int g = 0; g < 4; ++g) {
                const int w = ((dh | (2 * g + hi)) ^ (R & 15)) << 4;
                short8v vf = *reinterpret_cast<const short8v*>(vr + w);
                o[dblk] = __builtin_amdgcn_mfma_f32_32x32x16_bf16(pf[g], vf, o[dblk], 0, 0, 0);
            }
        }
        __builtin_amdgcn_s_setprio(0);

        __syncthreads();       // drains staged loads + LDS reads
        buf ^= 1;
    }

    // ---- merge halves via LDS (aliases staging buffers) ----
    float* smO = (float*)lds;                 // [4][32][128] = 64 KB
    float* smM = (float*)(lds + 65536);       // [4][32]
    float* smL = (float*)(lds + 66048);       // [4][32]

    if (h == 1) {
        if (hi == 0) { smM[qt * 32 + l31] = m_run; smL[qt * 32 + l31] = l_run; }
#pragma unroll
        for (int dblk = 0; dblk < 4; ++dblk)
#pragma unroll
            for (int reg = 0; reg < 16; ++reg) {
                const int qp = (reg & 3) + 8 * (reg >> 2) + 4 * hi;
                smO[(qt * 32 + qp) * 128 + dblk * 32 + l31] = o[dblk][reg];
            }
    }
    __syncthreads();
    if (h == 0) {
        const float m1 = smM[qt * 32 + l31];
        const float l1 = smL[qt * 32 + l31];
        const float mf = fmaxf(m_run, m1);
        const float a0 = exp2f(m_run - mf);
        const float a1 = exp2f(m1 - mf);
        const float li = 1.0f / (l_run * a0 + l1 * a1);
        const float w0 = a0 * li;
        const float w1 = a1 * li;

        float w0q[16], w1q[16];
#pragma unroll
        for (int reg = 0; reg < 16; ++reg) {
            const int qp = (reg & 3) + 8 * (reg >> 2) + 4 * hi;
            w0q[reg] = __shfl(w0, qp);
            w1q[reg] = __shfl(w1, qp);
        }

        float* ob = out + ((size_t)b * SEQ + q0) * DK;
#pragma unroll
        for (int dblk = 0; dblk < 4; ++dblk)
#pragma unroll
            for (int reg = 0; reg < 16; ++reg) {
                const int qp = (reg & 3) + 8 * (reg >> 2) + 4 * hi;
                ob[(size_t)qp * DK + dblk * 32 + l31] =
                    o[dblk][reg] * w0q[reg]
                    + smO[(qt * 32 + qp) * 128 + dblk * 32 + l31] * w1q[reg];
            }
    }
}

// ---------------- fallback (round-1 kernel) if ws too small -----------
__global__ __launch_bounds__(256)
void attn_fwd_slow(const float* __restrict__ q,
                   const float* __restrict__ k,
                   const float* __restrict__ v,
                   float* __restrict__ out)
{
    const int lane = threadIdx.x & 63;
    const int wave = threadIdx.x >> 6;
    const int b    = blockIdx.y;
    const int q0   = blockIdx.x * 64 + wave * 16;
    const int row = lane & 15;
    const int grp = lane >> 4;

    const float* qb = q + ((size_t)b * SEQ + q0) * DK;
    const float* kbp = k + (size_t)b * SEQ * DK;
    const float* vbp = v + (size_t)b * SEQ * DK;

    short8v qf[4];
#pragma unroll
    for (int c = 0; c < 4; ++c) {
        const float* p = qb + row * DK + c * 32 + grp * 8;
        float4 x = *reinterpret_cast<const float4*>(p);
        float4 y = *reinterpret_cast<const float4*>(p + 4);
        short8v t;
        t[0] = f2bf(x.x); t[1] = f2bf(x.y); t[2] = f2bf(x.z); t[3] = f2bf(x.w);
        t[4] = f2bf(y.x); t[5] = f2bf(y.y); t[6] = f2bf(y.z); t[7] = f2bf(y.w);
        qf[c] = t;
    }

    float m_run = -1e30f, l_run = 0.0f;
    float4v o[8];
#pragma unroll
    for (int i = 0; i < 8; ++i) { o[i][0]=0.f; o[i][1]=0.f; o[i][2]=0.f; o[i][3]=0.f; }
    const float scale = 0.08838834764831845f;

    for (int kv0 = 0; kv0 < SEQ; kv0 += 16) {
        short8v kf[4];
        const float* kp0 = kbp + (size_t)(kv0 + row) * DK + grp * 8;
#pragma unroll
        for (int c = 0; c < 4; ++c) {
            const float* p = kp0 + c * 32;
            float4 x = *reinterpret_cast<const float4*>(p);
            float4 y = *reinterpret_cast<const float4*>(p + 4);
            short8v t;
            t[0] = f2bf(x.x); t[1] = f2bf(x.y); t[2] = f2bf(x.z); t[3] = f2bf(x.w);
            t[4] = f2bf(y.x); t[5] = f2bf(y.y); t[6] = f2bf(y.z); t[7] = f2bf(y.w);
            kf[c] = t;
        }
        short8v vf[8];
#pragma unroll
        for (int dblk = 0; dblk < 8; ++dblk) {
            const float* p = vbp + (size_t)(kv0 + 4 * grp) * DK + dblk * 16 + row;
            short b0 = f2bf(p[0]);
            short b1 = f2bf(p[DK]);
            short b2 = f2bf(p[2 * DK]);
            short b3 = f2bf(p[3 * DK]);
            short8v t;
            t[0]=b0; t[1]=b1; t[2]=b2; t[3]=b3; t[4]=b0; t[5]=b1; t[6]=b2; t[7]=b3;
            vf[dblk] = t;
        }
        float4v s; s[0]=0.f; s[1]=0.f; s[2]=0.f; s[3]=0.f;
#pragma unroll
        for (int c = 0; c < 4; ++c)
            s = __builtin_amdgcn_mfma_f32_16x16x32_bf16(kf[c], qf[c], s, 0, 0, 0);

        float sv[4]; float tmax = -1e30f;
#pragma unroll
        for (int r = 0; r < 4; ++r) { sv[r] = s[r] * scale; tmax = fmaxf(tmax, sv[r]); }
        tmax = fmaxf(tmax, __shfl_xor(tmax, 16));
        tmax = fmaxf(tmax, __shfl_xor(tmax, 32));
        const float mnew = fmaxf(m_run, tmax);
        float pr[4]; float tsum = 0.f;
#pragma unroll
        for (int r = 0; r < 4; ++r) { pr[r] = __expf(sv[r] - mnew); tsum += pr[r]; }
        tsum += __shfl_xor(tsum, 16);
        tsum += __shfl_xor(tsum, 32);
        const float alpha = __expf(m_run - mnew);
        l_run = l_run * alpha + tsum;
        m_run = mnew;
        float aq[4];
#pragma unroll
        for (int r = 0; r < 4; ++r) aq[r] = __shfl(alpha, grp * 4 + r);
#pragma unroll
        for (int dblk = 0; dblk < 8; ++dblk)
#pragma unroll
            for (int r = 0; r < 4; ++r) o[dblk][r] *= aq[r];

        short8v pfv;
        pfv[0]=f2bf(pr[0]); pfv[1]=f2bf(pr[1]); pfv[2]=f2bf(pr[2]); pfv[3]=f2bf(pr[3]);
        pfv[4]=0; pfv[5]=0; pfv[6]=0; pfv[7]=0;
#pragma unroll
        for (int dblk = 0; dblk < 8; ++dblk)
            o[dblk] = __builtin_amdgcn_mfma_f32_16x16x32_bf16(pfv, vf[dblk], o[dblk], 0, 0, 0);
    }

    const float linv = 1.0f / l_run;
    float li[4];
#pragma unroll
    for (int r = 0; r < 4; ++r) li[r] = __shfl(linv, grp * 4 + r);
    float* ob = out + ((size_t)b * SEQ + q0) * DK;
#pragma unroll
    for (int dblk = 0; dblk < 8; ++dblk)
#pragma unroll
        for (int r = 0; r < 4; ++r)
            ob[(size_t)(grp * 4 + r) * DK + dblk * 16 + row] = o[dblk][r] * li[r];
}

extern "C" void kernel_launch(void* const* d_in, const int* in_sizes, int n_in,
                              void* d_out, int out_size, void* d_ws, size_t ws_size,
                              hipStream_t stream) {
    const float* q = (const float*)d_in[0];
    const float* k = (const float*)d_in[1];
    const float* v = (const float*)d_in[2];
    float* out = (float*)d_out;

    const size_t kb_bytes = (size_t)BATCH * SEQ * DK * sizeof(short);
    const size_t need = 2 * kb_bytes;

    if (ws_size >= need) {
        short* kb = (short*)d_ws;
        short* vt = (short*)((char*)d_ws + kb_bytes);
        hipLaunchKernelGGL(conv_k_kernel, dim3(2048), dim3(256), 0, stream, k, kb);
        hipLaunchKernelGGL(transpose_v_kernel, dim3(SEQ / 32, DK / 32, BATCH), dim3(256), 0, stream, v, vt);
        hipLaunchKernelGGL(attn_fwd_v6, dim3(SEQ / 128, BATCH), dim3(512), 0, stream, q, kb, vt, out);
    } else {
        hipLaunchKernelGGL(attn_fwd_slow, dim3(SEQ / 64, BATCH), dim3(256), 0, stream, q, k, v, out);
    }
}